// Round 5
// baseline (97.030 us; speedup 1.0000x reference)
//
#include <hip/hip_runtime.h>
#include <math.h>

#define PH 7
#define PW 7
#define BB 4
#define HH 64
#define WW 64
#define CC 256
#define RR 128
#define CH4 (CC / 4)                   // 64 float4 per pixel
#define BINS_PER_IMG (RR * PH * PW)    // 6272
#define NBINS (BB * BINS_PER_IMG)      // 25088
#define NBLK (NBINS / 4)               // 6272 blocks, 4 waves each
#define BLK_PER_IMG (NBLK / 8)         // 784
#define P2H 32
#define P2W 32
#define P2_BYTES ((size_t)BB * P2H * P2W * CC * 4)   // 4 MiB

typedef float f4 __attribute__((ext_vector_type(4)));

__device__ __forceinline__ f4 max4(f4 a, f4 b) {
    f4 r;
    r.x = fmaxf(a.x, b.x); r.y = fmaxf(a.y, b.y);
    r.z = fmaxf(a.z, b.z); r.w = fmaxf(a.w, b.w);
    return r;
}
__device__ __forceinline__ int rfl(int x) { return __builtin_amdgcn_readfirstlane(x); }

// ---- Pass 1: P2[b][h2][w2][C] = max of aligned 2x2 fm block. 1024 blocks. ----
__global__ __launch_bounds__(256) void build_p2_kernel(
    const float* __restrict__ fm, float* __restrict__ p2)
{
    const int lane = threadIdx.x & 63;
    const int wave = rfl((int)threadIdx.x >> 6);
    const int bid  = blockIdx.x;                 // 1024 = 8 xcd * 128
    const int xcd  = bid & 7;
    const int b    = xcd >> 1;
    const int idx  = (xcd & 1) * 128 + (bid >> 3);   // 0..255
    const int local = idx * 4 + wave;                // 0..1023 = h2*32+w2
    const int h2 = local >> 5, w2 = local & 31;

    const f4* src = (const f4*)fm + (((size_t)b * HH + 2 * h2) * WW + 2 * w2) * CH4 + lane;
    f4 v0 = src[0], v1 = src[CH4], v2 = src[WW * CH4], v3 = src[WW * CH4 + CH4];
    ((f4*)p2)[((size_t)b * (P2H * P2W) + local) * CH4 + lane] = max4(max4(v0, v1), max4(v2, v3));
}

// ---- Pass 2: one wave per bin; interior from P2, edges from fm. ----
__global__ __launch_bounds__(256) void ROIPoolingLayer_62079457296467_kernel(
    const float* __restrict__ fm, const float* __restrict__ rois,
    const float* __restrict__ p2, float* __restrict__ out)
{
    const int lane = threadIdx.x & 63;
    const int wave = rfl((int)threadIdx.x >> 6);

    const int bid   = blockIdx.x;                // 6272 = 8 xcd * 784
    const int xcd   = bid & 7;
    const int b     = xcd >> 1;
    const int blkin = (xcd & 1) * BLK_PER_IMG + (bid >> 3);
    const int local = blkin * 4 + wave;          // 0..6271 = r*49 + bin
    const int r     = local / (PH * PW);
    const int bin   = local - r * (PH * PW);
    const int ph    = bin / PW;
    const int pw    = bin - ph * PW;

    // ROI decode (reference fp32 semantics)
    const f4 roi = ((const f4*)rois)[b * RR + r];
    const int h0 = rfl((int)floorf((float)HH * roi.x));
    const int w0 = rfl((int)floorf((float)WW * roi.y));
    const int h1 = rfl((int)floorf((float)HH * roi.z));
    const int w1 = rfl((int)floorf((float)WW * roi.w));
    const int rh = h1 - h0, rw = w1 - w0;
    const int hstep = max(rh / PH, 1), wstep = max(rw / PW, 1);

    int hs = h0 + ph * hstep;
    int he = (ph == PH - 1) ? (h0 + rh) : (hs + hstep);
    he = min(he, h0 + rh);  he = min(he, HH);
    int ws = w0 + pw * wstep;
    int we = (pw == PW - 1) ? (w0 + rw) : (ws + wstep);
    we = min(we, w0 + rw);  we = min(we, WW);

    const f4* fmb = (const f4*)fm + (size_t)b * (HH * WW) * CH4 + lane;
    const f4* p2b = (const f4*)p2 + (size_t)b * (P2H * P2W) * CH4 + lane;
    f4 acc = (f4){-INFINITY, -INFINITY, -INFINITY, -INFINITY};

    if (he > hs && we > ws) {
        const int wbin = we - ws;
        // Aligned interior (P2 coords) + edge strips. All spans <= 1 wide.
        const int h2s = (hs + 1) >> 1, h2e = he >> 1;
        const int w2s = (ws + 1) >> 1, w2e = we >> 1;
        const int n2h = max(h2e - h2s, 0), n2w = max(w2e - w2s, 0);
        const int il0 = 2 * h2s, il1 = max(2 * h2e, il0);   // interior fm rows
        const int jl0 = 2 * w2s, jl1 = max(2 * w2e, jl0);   // interior fm cols

        // -- interior: n2h x n2w P2 loads --
        const int nint = n2h * n2w;
        if (nint > 0) {
            const unsigned m = (65536u + (unsigned)n2w - 1) / (unsigned)n2w;
            for (int p = 0; p < nint; p += 8) {
                f4 v[8];
#pragma unroll
                for (int k = 0; k < 8; ++k) {
                    const int pk = min(p + k, nint - 1);
                    const int q  = (int)(((unsigned)pk * m) >> 16);
                    const int c  = pk - q * n2w;
                    const int off = rfl((h2s + q) * P2W + (w2s + c));
                    v[k] = p2b[(size_t)off * CH4];
                }
#pragma unroll
                for (int k = 0; k < 4; ++k) v[k] = max4(v[k], v[k + 4]);
                acc = max4(acc, max4(max4(v[0], v[1]), max4(v[2], v[3])));
            }
        }

        // -- h-edge rows (<=2, full bin width) --
        const int t1 = min(il0, he);                  // top: [hs, t1)
        const int b0 = max(il1, hs);                  // bottom: [b0, he)
        const int nt = max(t1 - hs, 0), nb = max(he - b0, 0);   // each 0/1
        const int nrow = nt + nb;
        const int rowA = nt ? hs : b0, rowB = b0;
        const int nhe = nrow * wbin;
        if (nhe > 0) {
            const unsigned m = (65536u + (unsigned)wbin - 1) / (unsigned)wbin;
            for (int p = 0; p < nhe; p += 8) {
                f4 v[8];
#pragma unroll
                for (int k = 0; k < 8; ++k) {
                    const int pk = min(p + k, nhe - 1);
                    const int q  = (int)(((unsigned)pk * m) >> 16);   // 0/1
                    const int rr2 = q ? rowB : rowA;
                    const int c  = ws + (pk - q * wbin);
                    const int off = rfl(rr2 * WW + c);
                    v[k] = fmb[(size_t)off * CH4];
                }
#pragma unroll
                for (int k = 0; k < 4; ++k) v[k] = max4(v[k], v[k + 4]);
                acc = max4(acc, max4(max4(v[0], v[1]), max4(v[2], v[3])));
            }
        }

        // -- v-edge cols (<=2) over interior rows [il0, il1) --
        const int ilen = il1 - il0;
        const int nl = max(min(jl0, we) - ws, 0);     // 0/1, col ws
        const int nr = max(we - max(jl1, ws), 0);     // 0/1, col we-1
        const int ncols = nl + nr;
        const int colA = nl ? ws : (we - 1), colB = we - 1;
        const int nve = ilen * ncols;
        if (nve > 0) {
            for (int p = 0; p < nve; p += 8) {
                f4 v[8];
#pragma unroll
                for (int k = 0; k < 8; ++k) {
                    const int pk = min(p + k, nve - 1);
                    const int hh = il0 + ((ncols == 2) ? (pk >> 1) : pk);
                    const int c  = (ncols == 2 && (pk & 1)) ? colB : colA;
                    const int off = rfl(hh * WW + c);
                    v[k] = fmb[(size_t)off * CH4];
                }
#pragma unroll
                for (int k = 0; k < 4; ++k) v[k] = max4(v[k], v[k + 4]);
                acc = max4(acc, max4(max4(v[0], v[1]), max4(v[2], v[3])));
            }
        }
    }

    const size_t gbin = (size_t)b * BINS_PER_IMG + local;
    __builtin_nontemporal_store(acc, (f4*)out + gbin * CH4 + lane);
}

// ---- Fallback (R4-style direct) if ws too small for P2 ----
__global__ __launch_bounds__(256) void roi_direct_kernel(
    const float* __restrict__ fm, const float* __restrict__ rois,
    float* __restrict__ out)
{
    const int lane = threadIdx.x & 63;
    const int wave = rfl((int)threadIdx.x >> 6);
    const int bid   = blockIdx.x;
    const int xcd   = bid & 7;
    const int b     = xcd >> 1;
    const int blkin = (xcd & 1) * BLK_PER_IMG + (bid >> 3);
    const int local = blkin * 4 + wave;
    const int r     = local / (PH * PW);
    const int bin   = local - r * (PH * PW);
    const int ph    = bin / PW;
    const int pw    = bin - ph * PW;
    const f4 roi = ((const f4*)rois)[b * RR + r];
    const int h0 = rfl((int)floorf((float)HH * roi.x));
    const int w0 = rfl((int)floorf((float)WW * roi.y));
    const int h1 = rfl((int)floorf((float)HH * roi.z));
    const int w1 = rfl((int)floorf((float)WW * roi.w));
    const int rh = h1 - h0, rw = w1 - w0;
    const int hstep = max(rh / PH, 1), wstep = max(rw / PW, 1);
    int hs = h0 + ph * hstep;
    int he = (ph == PH - 1) ? (h0 + rh) : (hs + hstep);
    he = min(he, h0 + rh);  he = min(he, HH);
    int ws = w0 + pw * wstep;
    int we = (pw == PW - 1) ? (w0 + rw) : (ws + wstep);
    we = min(we, w0 + rw);  we = min(we, WW);
    const int wbin = we - ws, npix = (he - hs) * wbin;
    const f4* fmb = (const f4*)fm + (((size_t)b * HH + hs) * WW + ws) * CH4 + lane;
    f4 acc = (f4){-INFINITY, -INFINITY, -INFINITY, -INFINITY};
    if (npix > 0) {
        const unsigned m = (65536u + (unsigned)wbin - 1) / (unsigned)wbin;
        for (int p = 0; p < npix; p += 8) {
            f4 v[8];
#pragma unroll
            for (int k = 0; k < 8; ++k) {
                const int pk = min(p + k, npix - 1);
                const int q  = (int)(((unsigned)pk * m) >> 16);
                const int off = rfl(q * WW + (pk - q * wbin));
                v[k] = fmb[(size_t)off * CH4];
            }
#pragma unroll
            for (int k = 0; k < 4; ++k) v[k] = max4(v[k], v[k + 4]);
            acc = max4(acc, max4(max4(v[0], v[1]), max4(v[2], v[3])));
        }
    }
    const size_t gbin = (size_t)b * BINS_PER_IMG + local;
    __builtin_nontemporal_store(acc, (f4*)out + gbin * CH4 + lane);
}

extern "C" void kernel_launch(void* const* d_in, const int* in_sizes, int n_in,
                              void* d_out, int out_size, void* d_ws, size_t ws_size,
                              hipStream_t stream) {
    const float* fm   = (const float*)d_in[0];
    const float* rois = (const float*)d_in[1];
    float* out        = (float*)d_out;
    if (ws_size >= P2_BYTES) {
        float* p2 = (float*)d_ws;
        build_p2_kernel<<<1024, 256, 0, stream>>>(fm, p2);
        ROIPoolingLayer_62079457296467_kernel<<<NBLK, 256, 0, stream>>>(fm, rois, p2, out);
    } else {
        roi_direct_kernel<<<NBLK, 256, 0, stream>>>(fm, rois, out);
    }
}

// Round 6
// 90.963 us; speedup vs baseline: 1.0667x; 1.0667x over previous
//
#include <hip/hip_runtime.h>
#include <math.h>

#define PH 7
#define PW 7
#define BB 4
#define HH 64
#define WW 64
#define CC 256
#define RR 128
#define CH4 (CC / 4)                   // 64 float4 per pixel
#define BINS_PER_IMG (RR * PH * PW)    // 6272
#define NBINS (BB * BINS_PER_IMG)      // 25088
#define NBLK (NBINS / 4)               // 6272 blocks, 4 waves each
#define BLK_PER_IMG (NBLK / 8)         // 784
#define P2S_BYTES ((size_t)BB * HH * WW * CC * 4)   // 16.8 MB (64x64 layout)
#define BUILD_BLK 1008                 // 4 img * 63 rows * 16 colgroups / 4

typedef float f4 __attribute__((ext_vector_type(4)));

__device__ __forceinline__ f4 max4(f4 a, f4 b) {
    f4 r;
    r.x = fmaxf(a.x, b.x); r.y = fmaxf(a.y, b.y);
    r.z = fmaxf(a.z, b.z); r.w = fmaxf(a.w, b.w);
    return r;
}
__device__ __forceinline__ int rfl(int x) { return __builtin_amdgcn_readfirstlane(x); }

// ---- Pass 1: dense sliding 2x2 max. P2s[b][h][w] = max fm[h..h+1][w..w+1],
// valid h,w in [0,62]. One wave per (b, h, 4-col group): 10 loads -> 4 outputs.
__global__ __launch_bounds__(256) void build_p2s_kernel(
    const float* __restrict__ fm, float* __restrict__ p2s)
{
    const int lane = threadIdx.x & 63;
    const int wave = rfl((int)threadIdx.x >> 6);
    const int bid  = blockIdx.x;                 // 1008 = 8 xcd * 126
    const int xcd  = bid & 7;
    const int b    = xcd >> 1;                   // image -> xcd pair (L2 warm)
    const int idx  = (xcd & 1) * 126 + (bid >> 3);   // 0..251
    const int local = idx * 4 + wave;                // 0..1007 = h*16 + wg
    const int h  = local >> 4;                       // 0..62
    const int c0 = (local & 15) * 4;                 // 0,4,..,60

    const f4* fb = (const f4*)fm + ((size_t)b * HH + h) * WW * CH4 + lane;
    f4 rm[5];
#pragma unroll
    for (int j = 0; j < 5; ++j) {
        const int c = min(c0 + j, WW - 1);
        f4 t = fb[(size_t)c * CH4];
        f4 u = fb[(size_t)(WW + c) * CH4];           // row h+1 (h<=62)
        rm[j] = max4(t, u);
    }
    f4* ob = (f4*)p2s + ((size_t)b * HH + h) * WW * CH4 + lane;
#pragma unroll
    for (int j = 0; j < 4; ++j)
        __builtin_nontemporal_store(max4(rm[j], rm[j + 1]), ob + (size_t)(c0 + j) * CH4);
}

// ---- Pass 2: one wave per bin; cover window with overlapping 2x2 blocks
// from P2s (idempotent max): rows min(hs+2i, he-2), cols min(ws+2j, we-2),
// i<ceil(hbin/2), j<ceil(wbin/2). ~4.8 loads/bin vs 15.2 direct, ONE loop.
__global__ __launch_bounds__(256) void ROIPoolingLayer_62079457296467_kernel(
    const float* __restrict__ fm, const float* __restrict__ rois,
    const float* __restrict__ p2s, float* __restrict__ out)
{
    const int lane = threadIdx.x & 63;
    const int wave = rfl((int)threadIdx.x >> 6);

    const int bid   = blockIdx.x;                // 6272 = 8 xcd * 784
    const int xcd   = bid & 7;
    const int b     = xcd >> 1;
    const int blkin = (xcd & 1) * BLK_PER_IMG + (bid >> 3);
    const int local = blkin * 4 + wave;          // 0..6271 = r*49 + bin
    const int r     = local / (PH * PW);
    const int bin   = local - r * (PH * PW);
    const int ph    = bin / PW;
    const int pw    = bin - ph * PW;

    // ROI decode (reference fp32 semantics, truncating casts)
    const f4 roi = ((const f4*)rois)[b * RR + r];
    const int h0 = rfl((int)floorf((float)HH * roi.x));
    const int w0 = rfl((int)floorf((float)WW * roi.y));
    const int h1 = rfl((int)floorf((float)HH * roi.z));
    const int w1 = rfl((int)floorf((float)WW * roi.w));
    const int rh = h1 - h0, rw = w1 - w0;
    const int hstep = max(rh / PH, 1), wstep = max(rw / PW, 1);

    int hs = h0 + ph * hstep;
    int he = (ph == PH - 1) ? (h0 + rh) : (hs + hstep);
    he = min(he, h0 + rh);  he = min(he, HH);
    int ws = w0 + pw * wstep;
    int we = (pw == PW - 1) ? (w0 + rw) : (ws + wstep);
    we = min(we, w0 + rw);  we = min(we, WW);

    const int hbin = he - hs, wbin = we - ws;
    f4 acc = (f4){-INFINITY, -INFINITY, -INFINITY, -INFINITY};

    if (hbin >= 2 && wbin >= 2) {
        // ---- pyramid path (always taken for this input distribution) ----
        const f4* pb = (const f4*)p2s + (size_t)b * (HH * WW) * CH4 + lane;
        const int nh = (hbin + 1) >> 1, nw = (wbin + 1) >> 1;
        const int npos = nh * nw;                    // typ 4-6, max ~36
        const unsigned m = (65536u + (unsigned)nw - 1) / (unsigned)nw;
        for (int p = 0; p < npos; p += 8) {
            f4 v[8];
#pragma unroll
            for (int k = 0; k < 8; ++k) {
                const int pk  = min(p + k, npos - 1);            // clamp: dup ok
                const int i   = (int)(((unsigned)pk * m) >> 16); // exact, pk*e<2^16
                const int j   = pk - i * nw;
                const int row = min(hs + 2 * i, he - 2);
                const int col = min(ws + 2 * j, we - 2);
                const int off = rfl(row * WW + col);
                v[k] = pb[(size_t)off * CH4];
            }
#pragma unroll
            for (int k = 0; k < 4; ++k) v[k] = max4(v[k], v[k + 4]);
            acc = max4(acc, max4(max4(v[0], v[1]), max4(v[2], v[3])));
        }
    } else if (hbin > 0 && wbin > 0) {
        // ---- direct fallback (thin/degenerate bin; safety only) ----
        const f4* fmb = (const f4*)fm + (((size_t)b * HH + hs) * WW + ws) * CH4 + lane;
        const int npix = hbin * wbin;
        const unsigned m = (65536u + (unsigned)wbin - 1) / (unsigned)wbin;
        for (int p = 0; p < npix; p += 8) {
            f4 v[8];
#pragma unroll
            for (int k = 0; k < 8; ++k) {
                const int pk = min(p + k, npix - 1);
                const int q  = (int)(((unsigned)pk * m) >> 16);
                const int off = rfl(q * WW + (pk - q * wbin));
                v[k] = fmb[(size_t)off * CH4];
            }
#pragma unroll
            for (int k = 0; k < 4; ++k) v[k] = max4(v[k], v[k + 4]);
            acc = max4(acc, max4(max4(v[0], v[1]), max4(v[2], v[3])));
        }
    }

    const size_t gbin = (size_t)b * BINS_PER_IMG + local;
    __builtin_nontemporal_store(acc, (f4*)out + gbin * CH4 + lane);
}

// ---- Full direct kernel (fallback if ws too small for P2s) ----
__global__ __launch_bounds__(256) void roi_direct_kernel(
    const float* __restrict__ fm, const float* __restrict__ rois,
    float* __restrict__ out)
{
    const int lane = threadIdx.x & 63;
    const int wave = rfl((int)threadIdx.x >> 6);
    const int bid   = blockIdx.x;
    const int xcd   = bid & 7;
    const int b     = xcd >> 1;
    const int blkin = (xcd & 1) * BLK_PER_IMG + (bid >> 3);
    const int local = blkin * 4 + wave;
    const int r     = local / (PH * PW);
    const int bin   = local - r * (PH * PW);
    const int ph    = bin / PW;
    const int pw    = bin - ph * PW;
    const f4 roi = ((const f4*)rois)[b * RR + r];
    const int h0 = rfl((int)floorf((float)HH * roi.x));
    const int w0 = rfl((int)floorf((float)WW * roi.y));
    const int h1 = rfl((int)floorf((float)HH * roi.z));
    const int w1 = rfl((int)floorf((float)WW * roi.w));
    const int rh = h1 - h0, rw = w1 - w0;
    const int hstep = max(rh / PH, 1), wstep = max(rw / PW, 1);
    int hs = h0 + ph * hstep;
    int he = (ph == PH - 1) ? (h0 + rh) : (hs + hstep);
    he = min(he, h0 + rh);  he = min(he, HH);
    int ws = w0 + pw * wstep;
    int we = (pw == PW - 1) ? (w0 + rw) : (ws + wstep);
    we = min(we, w0 + rw);  we = min(we, WW);
    const int wbin = we - ws, npix = (he - hs) * wbin;
    const f4* fmb = (const f4*)fm + (((size_t)b * HH + hs) * WW + ws) * CH4 + lane;
    f4 acc = (f4){-INFINITY, -INFINITY, -INFINITY, -INFINITY};
    if (npix > 0) {
        const unsigned m = (65536u + (unsigned)wbin - 1) / (unsigned)wbin;
        for (int p = 0; p < npix; p += 8) {
            f4 v[8];
#pragma unroll
            for (int k = 0; k < 8; ++k) {
                const int pk = min(p + k, npix - 1);
                const int q  = (int)(((unsigned)pk * m) >> 16);
                const int off = rfl(q * WW + (pk - q * wbin));
                v[k] = fmb[(size_t)off * CH4];
            }
#pragma unroll
            for (int k = 0; k < 4; ++k) v[k] = max4(v[k], v[k + 4]);
            acc = max4(acc, max4(max4(v[0], v[1]), max4(v[2], v[3])));
        }
    }
    const size_t gbin = (size_t)b * BINS_PER_IMG + local;
    __builtin_nontemporal_store(acc, (f4*)out + gbin * CH4 + lane);
}

extern "C" void kernel_launch(void* const* d_in, const int* in_sizes, int n_in,
                              void* d_out, int out_size, void* d_ws, size_t ws_size,
                              hipStream_t stream) {
    const float* fm   = (const float*)d_in[0];
    const float* rois = (const float*)d_in[1];
    float* out        = (float*)d_out;
    if (ws_size >= P2S_BYTES) {
        float* p2s = (float*)d_ws;
        build_p2s_kernel<<<BUILD_BLK, 256, 0, stream>>>(fm, p2s);
        ROIPoolingLayer_62079457296467_kernel<<<NBLK, 256, 0, stream>>>(fm, rois, p2s, out);
    } else {
        roi_direct_kernel<<<NBLK, 256, 0, stream>>>(fm, rois, out);
    }
}